// Round 6
// baseline (2391.710 us; speedup 1.0000x reference)
//
#include <hip/hip_runtime.h>

typedef float f32x4 __attribute__((ext_vector_type(4)));
typedef float f32x16 __attribute__((ext_vector_type(16)));
typedef int i32x4 __attribute__((ext_vector_type(4)));
typedef int i32x8 __attribute__((ext_vector_type(8)));

#define M_DIM 16384L
#define N_DIM 4096L
#define K_DIM 4096L

// ---------------------------------------------------------------------------
// f32 -> OCP e4m3fn, RNE + saturation, bit-exact software version.
// ---------------------------------------------------------------------------
__device__ __forceinline__ unsigned int f32_to_e4m3(float x, float scale) {
  float v = fminf(fmaxf(x * scale, -448.f), 448.f);
  unsigned int u = __float_as_uint(v);
  unsigned int s = (u >> 24) & 0x80u;
  float ax = fabsf(v);
  unsigned int ua = __float_as_uint(ax);
  unsigned int subn = (unsigned int)rintf(ax * 512.0f);   // 0..8, RNE (subnormals)
  unsigned int r = ua + 0x7FFFFu + ((ua >> 20) & 1u);     // RNE to 3 mantissa bits
  unsigned int nrm = ((r >> 20) & 0x7FFu) - 960u;         // rebias 127 -> 7
  unsigned int mag = (ax < 0.015625f) ? subn : nrm;
  return mag | s;
}

__device__ __forceinline__ unsigned int pack4_e4m3(float4 v, float scale) {
  return f32_to_e4m3(v.x, scale) | (f32_to_e4m3(v.y, scale) << 8) |
         (f32_to_e4m3(v.z, scale) << 16) | (f32_to_e4m3(v.w, scale) << 24);
}

// ---------------------------------------------------------------------------
// Kernel 1: f32 -> packed e4m3 quantize (memory-bound).
// ---------------------------------------------------------------------------
__global__ __launch_bounds__(256) void quant_fp8(const float* __restrict__ in,
                                                 unsigned int* __restrict__ out,
                                                 float scale) {
  const long i = (long)blockIdx.x * 256 + threadIdx.x;
  out[i] = pack4_e4m3(reinterpret_cast<const float4*>(in)[i], scale);
}

// ---------------------------------------------------------------------------
// Shared helpers
// ---------------------------------------------------------------------------
__device__ __forceinline__ void gld_lds16(const unsigned char* g, unsigned char* l) {
  __builtin_amdgcn_global_load_lds(
      (const __attribute__((address_space(1))) unsigned int*)g,
      (__attribute__((address_space(3))) unsigned int*)l,
      16, 0, 0);
}

__device__ __forceinline__ uint4 quant16(const float* p, float scale) {
  const float4* q = reinterpret_cast<const float4*>(p);
  uint4 r;
  r.x = pack4_e4m3(q[0], scale);
  r.y = pack4_e4m3(q[1], scale);
  r.z = pack4_e4m3(q[2], scale);
  r.w = pack4_e4m3(q[3], scale);
  return r;
}

// two ds_read_b128 at swizzled 16B units p_lo, p_lo^1 -> 32B K-fragment
__device__ __forceinline__ i32x8 ldfrag2(const unsigned char* p, int p_lo, int ldr) {
  i32x4 lo = *reinterpret_cast<const i32x4*>(p + p_lo * 16);
  i32x4 hi = *reinterpret_cast<const i32x4*>(p + (p_lo ^ 1) * 16);
  (void)ldr;
  return i32x8{lo[0], lo[1], lo[2], lo[3], hi[0], hi[1], hi[2], hi[3]};
}

// fmtA=fmtB=0 (e4m3), scales = e8m0 127 = 1.0 -> bit-exact plain fp8 matmul
#define MFMA_SC(a, b, c) \
  __builtin_amdgcn_mfma_scale_f32_32x32x64_f8f6f4((a), (b), (c), 0, 0, 0, 0x7F7F7F7F, 0, 0x7F7F7F7F)

// ---------------------------------------------------------------------------
// Kernel 2 (main path): 128x128 tile, BK=128, 4 waves, single-buffered
// R2-proven 2-sync structure.  R5 post-mortem: barrier *style* is not the
// lever (R3/R4/R5 all ~370-412); per-round fixed cost (latency tails +
// barrier skew ~450 cyc) paid 64x is.  BK=128 halves the round count and
// doubles MFMA work per round at unchanged occupancy (fp8 tiles are tiny:
// 2 x 16 KB LDS; VGPR ~110 under launch_bounds(256,4) -> 4 blocks/CU).
//
// LDS layout at BK=128: row = 128 B = 8 x 16B units; row stride = 32 banks,
// so row drops out of the bank index -> 3-bit swizzle key required:
//   LDS (row, unit p) holds global unit p ^ (row & 7)   (involution).
// Fragment read (k-step s, lane group g=lane>>5): wants in-slab units
// u = 4s+2g+{0,1} at positions p = u ^ (r32 & 7); bank enumeration: every
// bank serves exactly 8 words per wave64 b128 = balanced floor.
// Fragment rows differ by multiples of 32 -> key = r32&7, wave-independent.
// Staging chunk l (of 1024/operand): row l>>3, LDS unit l&7, global unit
// (l&7) ^ ((l>>3)&7)  (j-independent for l = t + 256j).
// ---------------------------------------------------------------------------
__global__ __launch_bounds__(256, 4) void gemm_fp8_128(
    const unsigned char* __restrict__ A8, const unsigned char* __restrict__ B8,
    const float* __restrict__ bias, float* __restrict__ C) {
  __shared__ unsigned char sA[128 * 128];  // 16 KB
  __shared__ unsigned char sB[128 * 128];  // 16 KB

  const int t = threadIdx.x;
  const int lane = t & 63;
  const int w = t >> 6;   // wave 0..3
  const int wm = w >> 1;  // 2x2 wave grid, each wave owns 64x64 of C
  const int wn = w & 1;
  const long bx = blockIdx.x;  // N tile (32)
  const long by = blockIdx.y;  // M tile (128)

  f32x16 acc[2][2] = {};

  // staging: thread t stages chunks l = t + 256j, j=0..3, per operand.
  // row_j = (t>>3) + 32j ; source unit c = (t&7) ^ ((t>>3)&7) (j-indep).
  const int srow = t >> 3;
  const int sc = (t & 7) ^ ((t >> 3) & 7);
  const unsigned char* gA0 = A8 + (by * 128 + srow) * K_DIM + sc * 16;
  const unsigned char* gB0 = B8 + (bx * 128 + srow) * K_DIM + sc * 16;
  const long rstep = 32 * K_DIM;  // +32 rows per j
  // LDS dest (wave-uniform; HW adds lane*16): chunk group j of wave w starts
  // at (w*64 + 256j)*16 = w*1024 + j*4096.
  const int wofs = w * 1024;

  // fragment geometry: lane reads row r32 = lane&31 (+32*frag, +64*wm/wn),
  // k-step s in-slab units u0 = 4s + 2*(lane>>5); positions u0^key, ^1.
  const int r32 = lane & 31;
  const int key = r32 & 7;
  const int g2 = (lane >> 5) << 1;
  const int p0 = g2 ^ key;        // k-step 0
  const int p1 = (4 + g2) ^ key;  // k-step 1
  const unsigned char* sAw = sA + (wm * 64 + r32) * 128;
  const unsigned char* sBw = sB + (wn * 64 + r32) * 128;

  for (int kt = 0; kt < (int)(K_DIM / 128); ++kt) {
    const long ko = (long)kt * 128;
#pragma unroll
    for (int j = 0; j < 4; ++j) {
      gld_lds16(gA0 + j * rstep + ko, sA + wofs + j * 4096);
      gld_lds16(gB0 + j * rstep + ko, sB + wofs + j * 4096);
    }
    __syncthreads();  // drains vmcnt -> tile kt published

    // k-step 0
    i32x8 af0 = ldfrag2(sAw, p0, 0);
    i32x8 af1 = ldfrag2(sAw + 32 * 128, p0, 0);
    i32x8 bf0 = ldfrag2(sBw, p0, 0);
    i32x8 bf1 = ldfrag2(sBw + 32 * 128, p0, 0);
    // k-step 1 (independent reads; compiler interleaves with MFMA below)
    i32x8 af2 = ldfrag2(sAw, p1, 0);
    i32x8 af3 = ldfrag2(sAw + 32 * 128, p1, 0);
    i32x8 bf2 = ldfrag2(sBw, p1, 0);
    i32x8 bf3 = ldfrag2(sBw + 32 * 128, p1, 0);

    __builtin_amdgcn_s_setprio(1);
    acc[0][0] = MFMA_SC(af0, bf0, acc[0][0]);
    acc[0][1] = MFMA_SC(af0, bf1, acc[0][1]);
    acc[1][0] = MFMA_SC(af1, bf0, acc[1][0]);
    acc[1][1] = MFMA_SC(af1, bf1, acc[1][1]);
    acc[0][0] = MFMA_SC(af2, bf2, acc[0][0]);
    acc[0][1] = MFMA_SC(af2, bf3, acc[0][1]);
    acc[1][0] = MFMA_SC(af3, bf2, acc[1][0]);
    acc[1][1] = MFMA_SC(af3, bf3, acc[1][1]);
    __builtin_amdgcn_s_setprio(0);
    __syncthreads();  // protect tile kt from next round's staging
  }

  // ---- epilogue: 32x32 C/D map: col = lane&31, row = (r&3)+8*(r>>2)+4*(lane>>5)
  const int mrow = 4 * (lane >> 5);
  const long gm_base = by * 128 + wm * 64;
  const long gn_base = bx * 128 + wn * 64 + r32;
#pragma unroll
  for (int nj = 0; nj < 2; ++nj) {
    const long gn = gn_base + nj * 32;
    const float bv = bias[gn];
#pragma unroll
    for (int mi = 0; mi < 2; ++mi) {
#pragma unroll
      for (int r = 0; r < 16; ++r) {
        const long gm = gm_base + mi * 32 + (r & 3) + 8 * (r >> 2) + mrow;
        C[gm * N_DIM + gn] = acc[mi][nj][r] * 4.0f + bv;
      }
    }
  }
}

// ---------------------------------------------------------------------------
// Fallback kernel (scratch-constrained paths): R2-verified 128x128 BK=64 MX
// kernel with fused in-register quantization during staging.
// ---------------------------------------------------------------------------
template <bool FA, bool FB>
__global__ __launch_bounds__(256) void gemm_fp8_fb(const unsigned char* __restrict__ A8,
                                                   const float* __restrict__ Af,
                                                   const unsigned char* __restrict__ B8,
                                                   const float* __restrict__ Bf,
                                                   const float* __restrict__ bias,
                                                   float* __restrict__ C) {
  __shared__ unsigned char sA[128 * 64];
  __shared__ unsigned char sB[128 * 64];

  const int t = threadIdx.x;
  const int lane = t & 63;
  const int w = t >> 6;
  const int wm = w >> 1;
  const int wn = w & 1;
  const long bx = blockIdx.x;
  const long by = blockIdx.y;

  f32x16 acc[2][2] = {};

  const int l0 = w * 64 + lane;
  const int l1 = l0 + 256;
  const int r0 = l0 >> 2, c0 = (l0 & 3) ^ ((l0 >> 3) & 3);
  const int r1 = l1 >> 2, c1 = (l1 & 3) ^ ((l1 >> 3) & 3);

  const unsigned char* gA0 = nullptr; const unsigned char* gA1 = nullptr;
  const float* fA0 = nullptr;         const float* fA1 = nullptr;
  if constexpr (FA) {
    fA0 = Af + (by * 128 + r0) * K_DIM + c0 * 16;
    fA1 = Af + (by * 128 + r1) * K_DIM + c1 * 16;
  } else {
    gA0 = A8 + (by * 128 + r0) * K_DIM + c0 * 16;
    gA1 = A8 + (by * 128 + r1) * K_DIM + c1 * 16;
  }
  const unsigned char* gB0 = nullptr; const unsigned char* gB1 = nullptr;
  const float* fB0 = nullptr;         const float* fB1 = nullptr;
  if constexpr (FB) {
    fB0 = Bf + (bx * 128 + r0) * K_DIM + c0 * 16;
    fB1 = Bf + (bx * 128 + r1) * K_DIM + c1 * 16;
  } else {
    gB0 = B8 + (bx * 128 + r0) * K_DIM + c0 * 16;
    gB1 = B8 + (bx * 128 + r1) * K_DIM + c1 * 16;
  }

  unsigned char* lA0 = sA + w * 1024;
  unsigned char* lA1 = sA + 4096 + w * 1024;
  unsigned char* lB0 = sB + w * 1024;
  unsigned char* lB1 = sB + 4096 + w * 1024;

  const int r32 = lane & 31;
  const int key = (lane >> 1) & 3;
  const int p_lo = ((lane >> 5) << 1) ^ key;
  const unsigned char* sAw = sA + wm * 4096;
  const unsigned char* sBw = sB + wn * 4096;

  for (int kt = 0; kt < (int)(K_DIM / 64); ++kt) {
    if constexpr (FA) {
      *reinterpret_cast<uint4*>(sA + l0 * 16) = quant16(fA0, 0.5f);
      *reinterpret_cast<uint4*>(sA + l1 * 16) = quant16(fA1, 0.5f);
      fA0 += 64; fA1 += 64;
    } else {
      gld_lds16(gA0, lA0);
      gld_lds16(gA1, lA1);
      gA0 += 64; gA1 += 64;
    }
    if constexpr (FB) {
      *reinterpret_cast<uint4*>(sB + l0 * 16) = quant16(fB0, 1.0f);
      *reinterpret_cast<uint4*>(sB + l1 * 16) = quant16(fB1, 1.0f);
      fB0 += 64; fB1 += 64;
    } else {
      gld_lds16(gB0, lB0);
      gld_lds16(gB1, lB1);
      gB0 += 64; gB1 += 64;
    }
    __syncthreads();

    i32x8 af[2], bf[2];
#pragma unroll
    for (int i = 0; i < 2; ++i) {
      i32x4 alo = *reinterpret_cast<const i32x4*>(sAw + (i * 32 + r32) * 64 + p_lo * 16);
      i32x4 ahi = *reinterpret_cast<const i32x4*>(sAw + (i * 32 + r32) * 64 + (p_lo ^ 1) * 16);
      af[i] = i32x8{alo[0], alo[1], alo[2], alo[3], ahi[0], ahi[1], ahi[2], ahi[3]};
      i32x4 blo = *reinterpret_cast<const i32x4*>(sBw + (i * 32 + r32) * 64 + p_lo * 16);
      i32x4 bhi = *reinterpret_cast<const i32x4*>(sBw + (i * 32 + r32) * 64 + (p_lo ^ 1) * 16);
      bf[i] = i32x8{blo[0], blo[1], blo[2], blo[3], bhi[0], bhi[1], bhi[2], bhi[3]};
    }

#pragma unroll
    for (int i = 0; i < 2; ++i) {
#pragma unroll
      for (int j = 0; j < 2; ++j) {
        acc[i][j] = MFMA_SC(af[i], bf[j], acc[i][j]);
      }
    }
    __syncthreads();
  }

  const int mrow = 4 * (lane >> 5);
  const long gm_base = by * 128 + wm * 64;
  const long gn_base = bx * 128 + wn * 64 + r32;
#pragma unroll
  for (int nj = 0; nj < 2; ++nj) {
    const long gn = gn_base + nj * 32;
    const float bv = bias[gn];
#pragma unroll
    for (int mi = 0; mi < 2; ++mi) {
#pragma unroll
      for (int r = 0; r < 16; ++r) {
        const long gm = gm_base + mi * 32 + (r & 3) + 8 * (r >> 2) + mrow;
        C[gm * N_DIM + gn] = acc[mi][nj][r] * 4.0f + bv;
      }
    }
  }
}

// ---------------------------------------------------------------------------
extern "C" void kernel_launch(void* const* d_in, const int* in_sizes, int n_in,
                              void* d_out, int out_size, void* d_ws, size_t ws_size,
                              hipStream_t stream) {
  const float* inp = (const float*)d_in[0];   // [4,4096,4096] f32
  const float* wgt = (const float*)d_in[1];   // [4096,4096] f32 (fp8 values upcast by harness)
  const float* bias = (const float*)d_in[2];  // [4096] f32
  float* out = (float*)d_out;

  const size_t A_BYTES = (size_t)(M_DIM * K_DIM);  // 64 MB
  const size_t B_BYTES = (size_t)(N_DIM * K_DIM);  // 16 MB

  if (ws_size >= A_BYTES + B_BYTES) {
    // main path: pre-quantize both operands into d_ws, BK=128 128^2 GEMM
    unsigned char* aq = (unsigned char*)d_ws;
    unsigned char* wq = (unsigned char*)d_ws + A_BYTES;
    quant_fp8<<<dim3((unsigned)(M_DIM * K_DIM / 1024)), dim3(256), 0, stream>>>(
        inp, (unsigned int*)aq, 0.5f);
    quant_fp8<<<dim3((unsigned)(N_DIM * K_DIM / 1024)), dim3(256), 0, stream>>>(
        wgt, (unsigned int*)wq, 1.0f);
    gemm_fp8_128<<<dim3((unsigned)(N_DIM / 128), (unsigned)(M_DIM / 128)),
                   dim3(256), 0, stream>>>(aq, wq, bias, out);
  } else if (ws_size >= B_BYTES) {
    unsigned char* wq = (unsigned char*)d_ws;
    quant_fp8<<<dim3((unsigned)(N_DIM * K_DIM / 1024)), dim3(256), 0, stream>>>(
        wgt, (unsigned int*)wq, 1.0f);
    gemm_fp8_fb<true, false><<<dim3((unsigned)(N_DIM / 128), (unsigned)(M_DIM / 128)),
                               dim3(256), 0, stream>>>(nullptr, inp, wq, nullptr, bias, out);
  } else {
    gemm_fp8_fb<true, true><<<dim3((unsigned)(N_DIM / 128), (unsigned)(M_DIM / 128)),
                              dim3(256), 0, stream>>>(nullptr, inp, nullptr, wgt, bias, out);
  }
}

// Round 7
// 779.551 us; speedup vs baseline: 3.0681x; 3.0681x over previous
//
#include <hip/hip_runtime.h>

typedef float f32x4 __attribute__((ext_vector_type(4)));
typedef float f32x16 __attribute__((ext_vector_type(16)));
typedef int i32x4 __attribute__((ext_vector_type(4)));
typedef int i32x8 __attribute__((ext_vector_type(8)));

#define M_DIM 16384L
#define N_DIM 4096L
#define K_DIM 4096L

// ---------------------------------------------------------------------------
// f32 -> OCP e4m3fn, RNE + saturation, bit-exact software version (kept for
// the scratch-constrained fallback paths that quantize during staging).
// ---------------------------------------------------------------------------
__device__ __forceinline__ unsigned int f32_to_e4m3(float x, float scale) {
  float v = fminf(fmaxf(x * scale, -448.f), 448.f);
  unsigned int u = __float_as_uint(v);
  unsigned int s = (u >> 24) & 0x80u;
  float ax = fabsf(v);
  unsigned int ua = __float_as_uint(ax);
  unsigned int subn = (unsigned int)rintf(ax * 512.0f);   // 0..8, RNE (subnormals)
  unsigned int r = ua + 0x7FFFFu + ((ua >> 20) & 1u);     // RNE to 3 mantissa bits
  unsigned int nrm = ((r >> 20) & 0x7FFu) - 960u;         // rebias 127 -> 7
  unsigned int mag = (ax < 0.015625f) ? subn : nrm;
  return mag | s;
}

__device__ __forceinline__ unsigned int pack4_e4m3(float4 v, float scale) {
  return f32_to_e4m3(v.x, scale) | (f32_to_e4m3(v.y, scale) << 8) |
         (f32_to_e4m3(v.z, scale) << 16) | (f32_to_e4m3(v.w, scale) << 24);
}

// ---------------------------------------------------------------------------
// Kernel 1: f32 -> packed e4m3 quantize, hardware-convert version.
// v_cvt_pk_fp8_f32 (gfx950: OCP e4m3fn, RNE) converts 2 f32 -> 2 fp8 in one
// instruction; explicit pre-clamp to +-448 reproduces the reference's
// clip-then-cast exactly (for |x|<=448 RNE convert is identical to the
// software path; clamp handles the rest).  16 floats/thread, grid-stride.
// ---------------------------------------------------------------------------
__device__ __forceinline__ unsigned int cvt_pk4(float a, float b, float c, float d) {
  unsigned int r;
  asm("v_cvt_pk_fp8_f32 %0, %1, %2\n\t"
      "v_cvt_pk_fp8_f32 %0, %3, %4 op_sel:[0,0,1]"
      : "=&v"(r) : "v"(a), "v"(b), "v"(c), "v"(d));
  return r;
}

__device__ __forceinline__ float clampq(float x, float scale) {
  return fminf(fmaxf(x * scale, -448.f), 448.f);
}

__device__ __forceinline__ unsigned int quant4_hw(float4 v, float scale) {
  return cvt_pk4(clampq(v.x, scale), clampq(v.y, scale),
                 clampq(v.z, scale), clampq(v.w, scale));
}

__global__ __launch_bounds__(256) void quant_fp8_hw(const float* __restrict__ in,
                                                    uint4* __restrict__ out,
                                                    float scale, long n16) {
  long i = (long)blockIdx.x * 256 + threadIdx.x;
  const long stride = (long)gridDim.x * 256;
  for (; i < n16; i += stride) {
    const float4* p = reinterpret_cast<const float4*>(in) + i * 4;
    float4 v0 = p[0], v1 = p[1], v2 = p[2], v3 = p[3];
    uint4 r;
    r.x = quant4_hw(v0, scale);
    r.y = quant4_hw(v1, scale);
    r.z = quant4_hw(v2, scale);
    r.w = quant4_hw(v3, scale);
    out[i] = r;
  }
}

// ---------------------------------------------------------------------------
// Shared helpers
// ---------------------------------------------------------------------------
__device__ __forceinline__ void gld_lds16(const unsigned char* g, unsigned char* l) {
  __builtin_amdgcn_global_load_lds(
      (const __attribute__((address_space(1))) unsigned int*)g,
      (__attribute__((address_space(3))) unsigned int*)l,
      16, 0, 0);
}

__device__ __forceinline__ uint4 quant16(const float* p, float scale) {
  const float4* q = reinterpret_cast<const float4*>(p);
  uint4 r;
  r.x = pack4_e4m3(q[0], scale);
  r.y = pack4_e4m3(q[1], scale);
  r.z = pack4_e4m3(q[2], scale);
  r.w = pack4_e4m3(q[3], scale);
  return r;
}

// fmtA=fmtB=0 (e4m3), scales = e8m0 127 = 1.0 -> bit-exact plain fp8 matmul
#define MFMA_SC(a, b, c) \
  __builtin_amdgcn_mfma_scale_f32_32x32x64_f8f6f4((a), (b), (c), 0, 0, 0, 0x7F7F7F7F, 0, 0x7F7F7F7F)

// ---------------------------------------------------------------------------
// Kernel 2: fp8 GEMM, C[m,n] = 4 * sum_k A[m,k]*B[n,k] + bias[n]
// R2-verified best structure (369 us measured): 128x128 tile, BK=64 fp8,
// 2-barrier K-loop, global_load_lds width-16 staging, 16B-unit XOR-swizzled
// LDS (conflicts at the b128 structural floor), MX 32x32x64 MFMA.
// Five schedule variants (R3-R6: 1-block 8-phase, 2-phase, 3-buf counted
// vmcnt, BK=128) all measured slower (370-1999); this is the plateau.
// ---------------------------------------------------------------------------
template <bool FA, bool FB>
__global__ __launch_bounds__(256) void gemm_fp8(const unsigned char* __restrict__ A8,
                                                const float* __restrict__ Af,
                                                const unsigned char* __restrict__ B8,
                                                const float* __restrict__ Bf,
                                                const float* __restrict__ bias,
                                                float* __restrict__ C) {
  __shared__ unsigned char sA[128 * 64];  // 8 KB, row-major, 64 B per row
  __shared__ unsigned char sB[128 * 64];

  const int t = threadIdx.x;
  const int lane = t & 63;
  const int w = t >> 6;   // wave 0..3
  const int wm = w >> 1;  // 2x2 wave grid, each wave owns 64x64 of C
  const int wn = w & 1;
  const long bx = blockIdx.x;  // N tile
  const long by = blockIdx.y;  // M tile

  f32x16 acc[2][2] = {};

  // staging: 512 chunks of 16 B per tile; thread stages chunks l0 = w*64+lane
  // and l1 = l0+256. chunk l -> row l>>2, 16B-col l&3.
  // Source column is XOR-swizzled by row bits 1-2 (involution):
  //   LDS (row, unit p) holds global unit  p ^ ((row>>1)&3).
  const int l0 = w * 64 + lane;
  const int l1 = l0 + 256;
  const int r0 = l0 >> 2, c0 = (l0 & 3) ^ ((l0 >> 3) & 3);
  const int r1 = l1 >> 2, c1 = (l1 & 3) ^ ((l1 >> 3) & 3);

  const unsigned char* gA0 = nullptr; const unsigned char* gA1 = nullptr;
  const float* fA0 = nullptr;         const float* fA1 = nullptr;
  if constexpr (FA) {
    fA0 = Af + (by * 128 + r0) * K_DIM + c0 * 16;
    fA1 = Af + (by * 128 + r1) * K_DIM + c1 * 16;
  } else {
    gA0 = A8 + (by * 128 + r0) * K_DIM + c0 * 16;
    gA1 = A8 + (by * 128 + r1) * K_DIM + c1 * 16;
  }
  const unsigned char* gB0 = nullptr; const unsigned char* gB1 = nullptr;
  const float* fB0 = nullptr;         const float* fB1 = nullptr;
  if constexpr (FB) {
    fB0 = Bf + (bx * 128 + r0) * K_DIM + c0 * 16;
    fB1 = Bf + (bx * 128 + r1) * K_DIM + c1 * 16;
  } else {
    gB0 = B8 + (bx * 128 + r0) * K_DIM + c0 * 16;
    gB1 = B8 + (bx * 128 + r1) * K_DIM + c1 * 16;
  }

  unsigned char* lA0 = sA + w * 1024;         // wave-uniform; HW adds lane*16
  unsigned char* lA1 = sA + 4096 + w * 1024;
  unsigned char* lB0 = sB + w * 1024;
  unsigned char* lB1 = sB + 4096 + w * 1024;

  // fragment addressing for mfma_scale_f32_32x32x64_f8f6f4:
  // lane reads row r32 = lane&31 (+32*frag, +64*wm/wn), K-bytes
  // [32*(lane>>5), +32) = 16B units u_lo = 2*(lane>>5), u_lo+1.
  // Swizzled positions: p_lo = u_lo ^ key, p_lo^1, key = (lane>>1)&3.
  const int r32 = lane & 31;
  const int key = (lane >> 1) & 3;
  const int p_lo = ((lane >> 5) << 1) ^ key;
  const unsigned char* sAw = sA + wm * 4096;  // wm*64 rows
  const unsigned char* sBw = sB + wn * 4096;

  for (int kt = 0; kt < (int)(K_DIM / 64); ++kt) {
    if constexpr (FA) {
      *reinterpret_cast<uint4*>(sA + l0 * 16) = quant16(fA0, 0.5f);
      *reinterpret_cast<uint4*>(sA + l1 * 16) = quant16(fA1, 0.5f);
      fA0 += 64; fA1 += 64;
    } else {
      gld_lds16(gA0, lA0);
      gld_lds16(gA1, lA1);
      gA0 += 64; gA1 += 64;
    }
    if constexpr (FB) {
      *reinterpret_cast<uint4*>(sB + l0 * 16) = quant16(fB0, 1.0f);
      *reinterpret_cast<uint4*>(sB + l1 * 16) = quant16(fB1, 1.0f);
      fB0 += 64; fB1 += 64;
    } else {
      gld_lds16(gB0, lB0);
      gld_lds16(gB1, lB1);
      gB0 += 64; gB1 += 64;
    }
    __syncthreads();  // drains vmcnt (global_load_lds) + lgkmcnt (ds_write)

    i32x8 af[2], bf[2];
#pragma unroll
    for (int i = 0; i < 2; ++i) {
      const unsigned char* pa = sAw + (i * 32 + r32) * 64;
      i32x4 alo = *reinterpret_cast<const i32x4*>(pa + p_lo * 16);
      i32x4 ahi = *reinterpret_cast<const i32x4*>(pa + (p_lo ^ 1) * 16);
      af[i] = i32x8{alo[0], alo[1], alo[2], alo[3], ahi[0], ahi[1], ahi[2], ahi[3]};
      const unsigned char* pb = sBw + (i * 32 + r32) * 64;
      i32x4 blo = *reinterpret_cast<const i32x4*>(pb + p_lo * 16);
      i32x4 bhi = *reinterpret_cast<const i32x4*>(pb + (p_lo ^ 1) * 16);
      bf[i] = i32x8{blo[0], blo[1], blo[2], blo[3], bhi[0], bhi[1], bhi[2], bhi[3]};
    }

#pragma unroll
    for (int i = 0; i < 2; ++i) {
#pragma unroll
      for (int j = 0; j < 2; ++j) {
        acc[i][j] = MFMA_SC(af[i], bf[j], acc[i][j]);
      }
    }
    __syncthreads();
  }

  // epilogue: 32x32 C/D map: col(n) = lane&31, row(m) = (r&3)+8*(r>>2)+4*(lane>>5)
  const int mrow = 4 * (lane >> 5);
  const long gm_base = by * 128 + wm * 64;
  const long gn_base = bx * 128 + wn * 64 + r32;
#pragma unroll
  for (int nj = 0; nj < 2; ++nj) {
    const long gn = gn_base + nj * 32;
    const float bv = bias[gn];
#pragma unroll
    for (int mi = 0; mi < 2; ++mi) {
#pragma unroll
      for (int r = 0; r < 16; ++r) {
        const long gm = gm_base + mi * 32 + (r & 3) + 8 * (r >> 2) + mrow;
        C[gm * N_DIM + gn] = acc[mi][nj][r] * 4.0f + bv;
      }
    }
  }
}

// ---------------------------------------------------------------------------
extern "C" void kernel_launch(void* const* d_in, const int* in_sizes, int n_in,
                              void* d_out, int out_size, void* d_ws, size_t ws_size,
                              hipStream_t stream) {
  const float* inp = (const float*)d_in[0];   // [4,4096,4096] f32
  const float* wgt = (const float*)d_in[1];   // [4096,4096] f32 (fp8 values upcast by harness)
  const float* bias = (const float*)d_in[2];  // [4096] f32
  float* out = (float*)d_out;

  dim3 grid((unsigned)(N_DIM / 128), (unsigned)(M_DIM / 128));  // 32 x 128
  const size_t A_BYTES = (size_t)(M_DIM * K_DIM);      // 64 MB
  const size_t B_BYTES = (size_t)(N_DIM * K_DIM);      // 16 MB

  if (ws_size >= A_BYTES + B_BYTES) {
    // main path: pre-quantize both operands into d_ws (HW cvt), pure fp8 GEMM
    unsigned char* aq = (unsigned char*)d_ws;
    unsigned char* wq = (unsigned char*)d_ws + A_BYTES;
    quant_fp8_hw<<<dim3(2048), dim3(256), 0, stream>>>(
        inp, (uint4*)aq, 0.5f, M_DIM * K_DIM / 16);
    quant_fp8_hw<<<dim3(2048), dim3(256), 0, stream>>>(
        wgt, (uint4*)wq, 1.0f, N_DIM * K_DIM / 16);
    gemm_fp8<false, false><<<grid, dim3(256), 0, stream>>>(aq, nullptr, wq, nullptr, bias, out);
  } else if (ws_size >= B_BYTES) {
    // quantize weight only; fuse A-quant into staging
    unsigned char* wq = (unsigned char*)d_ws;
    quant_fp8_hw<<<dim3(2048), dim3(256), 0, stream>>>(
        wgt, (uint4*)wq, 1.0f, N_DIM * K_DIM / 16);
    gemm_fp8<true, false><<<grid, dim3(256), 0, stream>>>(nullptr, inp, wq, nullptr, bias, out);
  } else {
    // no scratch: fuse both quantizations into staging
    gemm_fp8<true, true><<<grid, dim3(256), 0, stream>>>(nullptr, inp, nullptr, wgt, bias, out);
  }
}